// Round 14
// baseline (172.165 us; speedup 1.0000x reference)
//
#include <hip/hip_runtime.h>

// BatchTopK: relu(x), keep global top (k*1024) of 1024*24576 fp32, zero rest.
// Exact radix-select on positive-fp32 bit patterns + index-ordered tie-break.
//
// R14: tail collapse by redundant per-block recompute (no fences, no
// coordinator kernels): k_main blocks each compute F from the sample
// replicas (deterministic, L2-hot); k_filter/k_select each compute
// b12/c_above from the H replicas. 5 launches: prep, main, fb(guarded),
// filter, select. k_main hot loop = R5 shape (fastest measured, 62-66us
// at the ~2.4TB/s context write wall established in R12).

#define N_ELEM   25165824            // 1024 * 24576
#define NV       (N_ELEM / 4)        // float4 count = 6291456 = 2048*256*12
#define HIST_SIZE 4096               // top-12-bit buckets
#define HREP     4                   // hist replicas
#define SREP     8                   // sample blocks / private replicas
#define NS       (NV / 256)          // sampled float4 count (1/256) = 24576
#define LCAP     1024                // per-block LDS candidate buffer
#define LCAP2    1024
#define TIE_CAP  4096
#define CAND2_CAP 262144
#define CAND_CAP  8388608

typedef float f32x4 __attribute__((ext_vector_type(4)));

// ws layout (uint32 words):
#define H_OFF     0                            // 4 x 4096 main hist (bits >= F)
#define H2_OFF    (H_OFF + HREP * HIST_SIZE)   // 16384: 4 x 4096 level-2 hist
#define HS_OFF    (H2_OFF + HREP * HIST_SIZE)  // 32768: 8 x 4096 sample replicas
#define META_OFF  (HS_OFF + SREP * HIST_SIZE)  // 65536: 32 words
#define CAND2_OFF (META_OFF + 32)              // 65568 (even -> uint2 ok)
#define CAND_OFF  (CAND2_OFF + 2 * CAND2_CAP)  // 589856 (even)
// meta: [0]=cand cnt  [7]=cand2 cnt   (cutoff params recomputed per block)

// K1 (8 blocks): zero H+H2+meta; 1/256 sample -> private replica.
__global__ void k_prep(const float4* __restrict__ x, unsigned* __restrict__ ws) {
    __shared__ unsigned lh[HIST_SIZE];
    for (int i = threadIdx.x; i < HIST_SIZE; i += 256) lh[i] = 0u;
    int gid = blockIdx.x * 256 + threadIdx.x;
    for (int i = gid; i < HS_OFF; i += SREP * 256) ws[i] = 0u;   // zero H + H2
    if (gid < 32) ws[META_OFF + gid] = 0u;
    __syncthreads();
    for (int s = gid; s < NS; s += SREP * 256) {
        int c = s >> 6, l = s & 63;          // 64 consecutive f4 per 16384-f4 chunk
        float4 v = x[c * 16384 + l];
        if (v.x > 0.0f) atomicAdd(&lh[__float_as_uint(v.x) >> 20], 1u);
        if (v.y > 0.0f) atomicAdd(&lh[__float_as_uint(v.y) >> 20], 1u);
        if (v.z > 0.0f) atomicAdd(&lh[__float_as_uint(v.z) >> 20], 1u);
        if (v.w > 0.0f) atomicAdd(&lh[__float_as_uint(v.w) >> 20], 1u);
    }
    __syncthreads();
    unsigned* hs = ws + HS_OFF + blockIdx.x * HIST_SIZE;
    for (int i = threadIdx.x; i < HIST_SIZE; i += 256) hs[i] = lh[i];
}

__device__ __forceinline__ void cand_push(unsigned b, unsigned idx,
                                          unsigned* lcnt, uint2* lc,
                                          unsigned* gcnt, uint2* cand, unsigned cap,
                                          unsigned* gh) {
    unsigned p = atomicAdd(lcnt, 1u);
    if (p < LCAP) lc[p] = make_uint2(b, idx);
    else {                                    // spill (~never): keep hist exact
        unsigned q = atomicAdd(gcnt, 1u);
        if (q < cap) { cand[q] = make_uint2(b, idx); atomicAdd(&gh[b >> 20], 1u); }
    }
}

// K2 (2048 x 256): per-block F pick (redundant, deterministic) + fused
// single-pass stream: {load f4, NT-store zero, compact >= F} x4-wide groups.
// Epilogue: block-local packed-u16 candidate histogram + single atomic flush.
__global__ __launch_bounds__(256) void k_main(const float4* __restrict__ x,
                                              float4* __restrict__ out,
                                              unsigned* __restrict__ ws,
                                              uint2* __restrict__ cand, unsigned cap,
                                              const int* __restrict__ kptr) {
    __shared__ unsigned pool[4096];          // phase A: sample hist; B: lc+lhp
    __shared__ unsigned ps[256];
    __shared__ unsigned F_sh, lcnt, gbase;
    const int t = threadIdx.x;
    // --- phase A: F = highest bucket with sampled suffix >= nk/128 ---
    for (int i = t; i < HIST_SIZE; i += 256) {
        unsigned s = 0u;
        #pragma unroll
        for (int r = 0; r < SREP; ++r) s += ws[HS_OFF + r * HIST_SIZE + i];
        pool[i] = s;
    }
    if (t == 0) F_sh = 1u;
    __syncthreads();
    unsigned nk = (unsigned)(*kptr) * 1024u;
    unsigned thr = nk / 128u; if (thr < 1u) thr = 1u;
    unsigned chunk = 0u;
    #pragma unroll
    for (int j = 0; j < 16; ++j) chunk += pool[t * 16 + j];
    ps[t] = chunk;
    __syncthreads();
    for (int st = 1; st < 256; st <<= 1) {
        unsigned v = (t + st < 256) ? ps[t + st] : 0u;
        __syncthreads();
        ps[t] += v;
        __syncthreads();
    }
    if (ps[0] >= thr) {
        unsigned S = (t < 255) ? ps[t + 1] : 0u;
        for (int j = 15; j >= 0; --j) {
            int b = t * 16 + j;
            unsigned Sb = S + pool[b];
            if (Sb >= thr && S < thr) F_sh = ((unsigned)b) << 20;
            S = Sb;
        }
    }
    __syncthreads();
    const unsigned F = F_sh;
    // --- phase B: stream; pool reused as lc[1024] (uint2) + lhp[2048] ---
    uint2* lc = reinterpret_cast<uint2*>(pool);
    unsigned* lhp = pool + 2048;
    if (t == 0) lcnt = 0u;
    for (int i = t; i < 2048; i += 256) lhp[i] = 0u;
    __syncthreads();
    unsigned* meta = ws + META_OFF;
    unsigned* gcnt = &meta[0];
    unsigned* gh = ws + H_OFF + (blockIdx.x & (HREP - 1)) * HIST_SIZE;
    const f32x4 z = {0.f, 0.f, 0.f, 0.f};
    int tid = blockIdx.x * 256 + t;
    const int stride = 2048 * 256;
    #pragma unroll
    for (int j = 0; j < 12; j += 4) {
        int i0 = tid + (j + 0) * stride;
        int i1 = tid + (j + 1) * stride;
        int i2 = tid + (j + 2) * stride;
        int i3 = tid + (j + 3) * stride;
        float4 v0 = x[i0];
        float4 v1 = x[i1];
        float4 v2 = x[i2];
        float4 v3 = x[i3];
        __builtin_nontemporal_store(z, (f32x4*)&out[i0]);
        __builtin_nontemporal_store(z, (f32x4*)&out[i1]);
        __builtin_nontemporal_store(z, (f32x4*)&out[i2]);
        __builtin_nontemporal_store(z, (f32x4*)&out[i3]);
        #pragma unroll
        for (int q = 0; q < 4; ++q) {
            float4 v = (q == 0) ? v0 : (q == 1) ? v1 : (q == 2) ? v2 : v3;
            int ii = (q == 0) ? i0 : (q == 1) ? i1 : (q == 2) ? i2 : i3;
            unsigned base = (unsigned)ii * 4u;
            unsigned b;
            b = __float_as_uint(fmaxf(v.x, 0.f)); if (b >= F) cand_push(b, base + 0u, &lcnt, lc, gcnt, cand, cap, gh);
            b = __float_as_uint(fmaxf(v.y, 0.f)); if (b >= F) cand_push(b, base + 1u, &lcnt, lc, gcnt, cand, cap, gh);
            b = __float_as_uint(fmaxf(v.z, 0.f)); if (b >= F) cand_push(b, base + 2u, &lcnt, lc, gcnt, cand, cap, gh);
            b = __float_as_uint(fmaxf(v.w, 0.f)); if (b >= F) cand_push(b, base + 3u, &lcnt, lc, gcnt, cand, cap, gh);
        }
    }
    __syncthreads();
    unsigned n = lcnt < LCAP ? lcnt : LCAP;
    for (unsigned e = t; e < n; e += 256) {
        unsigned b12 = lc[e].x >> 20;
        atomicAdd(&lhp[b12 >> 1], 1u << ((b12 & 1u) * 16u));
    }
    __syncthreads();
    if (t == 0 && n) gbase = atomicAdd(gcnt, n);
    __syncthreads();
    for (unsigned e = t; e < n; e += 256) {
        unsigned q = gbase + e;
        if (q < cap) cand[q] = lc[e];
    }
    for (int i = t; i < 2048; i += 256) {
        unsigned w = lhp[i];
        if (w & 0xFFFFu) atomicAdd(&gh[i * 2],     w & 0xFFFFu);
        if (w >> 16)     atomicAdd(&gh[i * 2 + 1], w >> 16);
    }
}

// K3 (2048, self-guarded): meta[0] == exact count(bits>=F). If >= nk, floor
// held -> no-op. Else complement pass (0 < bits < F) restores exactness.
__global__ void k_fb(const float4* __restrict__ x, unsigned* __restrict__ ws,
                     uint2* __restrict__ cand, unsigned cap,
                     const int* __restrict__ kptr) {
    unsigned* meta = ws + META_OFF;
    unsigned nk = (unsigned)(*kptr) * 1024u;
    if (meta[0] >= nk) return;               // floor held (normal path)
    __shared__ uint2 lc[LCAP];
    __shared__ unsigned lhp[HIST_SIZE / 2];
    __shared__ unsigned lcnt, gbase;
    if (threadIdx.x == 0) lcnt = 0u;
    for (int i = threadIdx.x; i < HIST_SIZE / 2; i += blockDim.x) lhp[i] = 0u;
    __syncthreads();
    // F recomputed the same way k_main did (deterministic).
    __shared__ unsigned pool2[4096];
    __shared__ unsigned ps[256];
    __shared__ unsigned F_sh;
    const int t = threadIdx.x;
    for (int i = t; i < HIST_SIZE; i += 256) {
        unsigned s = 0u;
        #pragma unroll
        for (int r = 0; r < SREP; ++r) s += ws[HS_OFF + r * HIST_SIZE + i];
        pool2[i] = s;
    }
    if (t == 0) F_sh = 1u;
    __syncthreads();
    unsigned thr = nk / 128u; if (thr < 1u) thr = 1u;
    unsigned chunk = 0u;
    #pragma unroll
    for (int j = 0; j < 16; ++j) chunk += pool2[t * 16 + j];
    ps[t] = chunk;
    __syncthreads();
    for (int st = 1; st < 256; st <<= 1) {
        unsigned v = (t + st < 256) ? ps[t + st] : 0u;
        __syncthreads();
        ps[t] += v;
        __syncthreads();
    }
    if (ps[0] >= thr) {
        unsigned S = (t < 255) ? ps[t + 1] : 0u;
        for (int j = 15; j >= 0; --j) {
            int b = t * 16 + j;
            unsigned Sb = S + pool2[b];
            if (Sb >= thr && S < thr) F_sh = ((unsigned)b) << 20;
            S = Sb;
        }
    }
    __syncthreads();
    const unsigned F = F_sh;
    unsigned* gcnt = &meta[0];
    unsigned* gh = ws + H_OFF + (blockIdx.x & (HREP - 1)) * HIST_SIZE;
    int stride = gridDim.x * blockDim.x;
    for (int i = blockIdx.x * blockDim.x + threadIdx.x; i < NV; i += stride) {
        float4 v = x[i];
        unsigned base = (unsigned)i * 4u;
        #pragma unroll
        for (int c = 0; c < 4; ++c) {
            float a = (c == 0) ? v.x : (c == 1) ? v.y : (c == 2) ? v.z : v.w;
            unsigned b = __float_as_uint(fmaxf(a, 0.f));
            if (b >= 1u && b < F) cand_push(b, base + (unsigned)c, &lcnt, lc, gcnt, cand, cap, gh);
        }
    }
    __syncthreads();
    unsigned n = lcnt < LCAP ? lcnt : LCAP;
    for (unsigned e = threadIdx.x; e < n; e += blockDim.x) {
        unsigned b12 = lc[e].x >> 20;
        atomicAdd(&lhp[b12 >> 1], 1u << ((b12 & 1u) * 16u));
    }
    __syncthreads();
    if (threadIdx.x == 0 && n) gbase = atomicAdd(gcnt, n);
    __syncthreads();
    for (unsigned e = threadIdx.x; e < n; e += blockDim.x) {
        unsigned q = gbase + e;
        if (q < cap) cand[q] = lc[e];
    }
    for (int i = threadIdx.x; i < HIST_SIZE / 2; i += blockDim.x) {
        unsigned w = lhp[i];
        if (w & 0xFFFFu) atomicAdd(&gh[i * 2],     w & 0xFFFFu);
        if (w >> 16)     atomicAdd(&gh[i * 2 + 1], w >> 16);
    }
}

// K4 (256 x 256): per-block scan of H (redundant) -> b12/c_above/keepall;
// scatter definite keepers (bucket > b12); compact ==b12 -> cand2 + H2.
__global__ __launch_bounds__(256) void k_filter(unsigned* __restrict__ ws,
                                                const uint2* __restrict__ cand,
                                                uint2* __restrict__ cand2,
                                                float* __restrict__ out, unsigned cap,
                                                const int* __restrict__ kptr) {
    __shared__ unsigned pool[4096];          // scan buf, then lc2[1024] (uint2)
    __shared__ unsigned ps[256];
    __shared__ unsigned b12_sh, ca_sh, lcnt, gbase;
    const int t = threadIdx.x;
    unsigned* meta = ws + META_OFF;
    unsigned nk = (unsigned)(*kptr) * 1024u;
    for (int i = t; i < HIST_SIZE; i += 256) {
        unsigned s = 0u;
        #pragma unroll
        for (int r = 0; r < HREP; ++r) s += ws[H_OFF + r * HIST_SIZE + i];
        pool[i] = s;
    }
    if (t == 0) lcnt = 0u;
    __syncthreads();
    unsigned chunk = 0u;
    #pragma unroll
    for (int j = 0; j < 16; ++j) chunk += pool[t * 16 + j];
    ps[t] = chunk;
    __syncthreads();
    for (int st = 1; st < 256; st <<= 1) {
        unsigned v = (t + st < 256) ? ps[t + st] : 0u;
        __syncthreads();
        ps[t] += v;
        __syncthreads();
    }
    unsigned total = ps[0];
    unsigned keepall = (total < nk) ? 1u : 0u;
    if (!keepall) {
        unsigned S = (t < 255) ? ps[t + 1] : 0u;
        for (int j = 15; j >= 0; --j) {
            int b = t * 16 + j;
            unsigned Sb = S + pool[b];
            if (Sb >= nk && S < nk) { b12_sh = (unsigned)b; ca_sh = S; }
            S = Sb;
        }
    }
    __syncthreads();
    unsigned ncand = meta[0]; if (ncand > cap) ncand = cap;
    unsigned stride = gridDim.x * blockDim.x;
    if (keepall) {
        for (unsigned i = blockIdx.x * blockDim.x + t; i < ncand; i += stride) {
            uint2 c = cand[i];
            out[c.y] = __uint_as_float(c.x);
        }
        return;
    }
    unsigned b12 = b12_sh;
    uint2* lc2 = reinterpret_cast<uint2*>(pool);    // scan data dead now
    unsigned* h2 = ws + H2_OFF + (blockIdx.x & (HREP - 1)) * HIST_SIZE;
    unsigned* cnt2 = &meta[7];
    for (unsigned i = blockIdx.x * blockDim.x + t; i < ncand; i += stride) {
        uint2 c = cand[i];
        unsigned bk = c.x >> 20;
        if (bk > b12) {
            out[c.y] = __uint_as_float(c.x);        // definite keeper
        } else if (bk == b12) {
            atomicAdd(&h2[(c.x >> 8) & 0xFFFu], 1u);
            unsigned p = atomicAdd(&lcnt, 1u);
            if (p < LCAP2) lc2[p] = c;
            else { unsigned q = atomicAdd(cnt2, 1u); if (q < CAND2_CAP) cand2[q] = c; }
        }
    }
    __syncthreads();
    unsigned n = lcnt < LCAP2 ? lcnt : LCAP2;
    if (t == 0 && n) gbase = atomicAdd(cnt2, n);
    __syncthreads();
    for (unsigned e = t; e < n; e += 256) {
        unsigned q = gbase + e;
        if (q < CAND2_CAP) cand2[q] = lc2[e];
    }
}

// K5 (1 block x 256): recompute b12/c_above; level-2/3 refinement -> exact
// tau; scatter in-bucket keepers (> tau) and the r lowest-index exact ties.
__global__ __launch_bounds__(256) void k_select(unsigned* __restrict__ ws,
                                                const uint2* __restrict__ cand2,
                                                float* __restrict__ out,
                                                const int* __restrict__ kptr) {
    __shared__ unsigned pool[4096];
    __shared__ unsigned ps[256];
    __shared__ unsigned h3[256];
    __shared__ int ties[TIE_CAP];
    __shared__ unsigned tie_cnt, b12_sh, ca_sh, s2_sh, ca2_sh, t3_sh, ca3_sh;
    const int t = threadIdx.x;
    unsigned* meta = ws + META_OFF;
    unsigned nk = (unsigned)(*kptr) * 1024u;
    // --- scan H for b12 / c_above (keepall handled by k_filter) ---
    for (int i = t; i < HIST_SIZE; i += 256) {
        unsigned s = 0u;
        #pragma unroll
        for (int r = 0; r < HREP; ++r) s += ws[H_OFF + r * HIST_SIZE + i];
        pool[i] = s;
    }
    if (t == 0) tie_cnt = 0u;
    h3[t] = 0u;
    __syncthreads();
    unsigned chunk = 0u;
    #pragma unroll
    for (int j = 0; j < 16; ++j) chunk += pool[t * 16 + j];
    ps[t] = chunk;
    __syncthreads();
    for (int st = 1; st < 256; st <<= 1) {
        unsigned v = (t + st < 256) ? ps[t + st] : 0u;
        __syncthreads();
        ps[t] += v;
        __syncthreads();
    }
    if (ps[0] < nk) return;                  // keepall case: filter did it
    {
        unsigned S = (t < 255) ? ps[t + 1] : 0u;
        for (int j = 15; j >= 0; --j) {
            int b = t * 16 + j;
            unsigned Sb = S + pool[b];
            if (Sb >= nk && S < nk) { b12_sh = (unsigned)b; ca_sh = S; }
            S = Sb;
        }
    }
    __syncthreads();
    unsigned b12 = b12_sh;
    unsigned m = nk - ca_sh;                 // rank within bucket b12, >=1
    unsigned n2 = meta[7]; if (n2 > CAND2_CAP) n2 = CAND2_CAP;
    // --- scan H2 for s2 / ca2 at rank m ---
    for (int i = t; i < HIST_SIZE; i += 256) {
        unsigned s = 0u;
        #pragma unroll
        for (int r = 0; r < HREP; ++r) s += ws[H2_OFF + r * HIST_SIZE + i];
        pool[i] = s;
    }
    __syncthreads();
    chunk = 0u;
    #pragma unroll
    for (int j = 0; j < 16; ++j) chunk += pool[t * 16 + j];
    ps[t] = chunk;
    __syncthreads();
    for (int st = 1; st < 256; st <<= 1) {
        unsigned v = (t + st < 256) ? ps[t + st] : 0u;
        __syncthreads();
        ps[t] += v;
        __syncthreads();
    }
    {
        unsigned S = (t < 255) ? ps[t + 1] : 0u;
        for (int j = 15; j >= 0; --j) {
            int b = t * 16 + j;
            unsigned Sb = S + pool[b];
            if (Sb >= m && S < m) { s2_sh = (unsigned)b; ca2_sh = S; }
            S = Sb;
        }
    }
    __syncthreads();
    unsigned s2 = s2_sh;
    unsigned m2 = m - ca2_sh;                // rank within sub-bucket, >=1
    // --- level-3 histogram over cand2 (bits[7:0] within s2) ---
    for (unsigned i = t; i < n2; i += 256) {
        uint2 c = cand2[i];
        if (((c.x >> 8) & 0xFFFu) == s2) atomicAdd(&h3[c.x & 0xFFu], 1u);
    }
    __syncthreads();
    ps[t] = h3[t];
    __syncthreads();
    for (int st = 1; st < 256; st <<= 1) {
        unsigned v = (t + st < 256) ? ps[t + st] : 0u;
        __syncthreads();
        ps[t] += v;
        __syncthreads();
    }
    {
        unsigned S3 = (t < 255) ? ps[t + 1] : 0u;
        unsigned Sb = S3 + h3[t];
        if (Sb >= m2 && S3 < m2) { t3_sh = (unsigned)t; ca3_sh = S3; }
    }
    __syncthreads();
    unsigned tau = (b12 << 20) | (s2 << 8) | t3_sh;
    unsigned r = m2 - ca3_sh;                // exact-tie keepers
    for (unsigned i = t; i < n2; i += 256) {
        uint2 c = cand2[i];
        if (c.x > tau) {
            out[c.y] = __uint_as_float(c.x); // in-bucket definite keeper
        } else if (c.x == tau) {
            unsigned q = atomicAdd(&tie_cnt, 1u);
            if (q < TIE_CAP) ties[q] = (int)c.y;
        }
    }
    __syncthreads();
    unsigned tc = tie_cnt; if (tc > TIE_CAP) tc = TIE_CAP;
    float tv = __uint_as_float(tau);
    for (unsigned e = t; e < tc; e += 256) {
        int my = ties[e];
        unsigned rank = 0u;
        for (unsigned j = 0; j < tc; ++j) rank += (ties[j] < my) ? 1u : 0u;
        if (rank < r) out[my] = tv;          // keep r lowest-index ties
    }
}

extern "C" void kernel_launch(void* const* d_in, const int* in_sizes, int n_in,
                              void* d_out, int out_size, void* d_ws, size_t ws_size,
                              hipStream_t stream) {
    const float4* x = (const float4*)d_in[0];
    const int* kptr = (const int*)d_in[1];
    float* out = (float*)d_out;
    unsigned* ws32 = (unsigned*)d_ws;
    uint2* cand2 = (uint2*)(ws32 + CAND2_OFF);
    uint2* cand  = (uint2*)(ws32 + CAND_OFF);

    unsigned cap = CAND_CAP;
    size_t hdr = (size_t)CAND_OFF * 4;
    if (ws_size < hdr + (size_t)CAND_CAP * 8) {
        cap = (ws_size > hdr) ? (unsigned)((ws_size - hdr) / 8) : 0u;
    }

    k_prep<<<SREP, 256, 0, stream>>>(x, ws32);
    k_main<<<2048, 256, 0, stream>>>(x, (float4*)out, ws32, cand, cap, kptr);
    k_fb<<<2048, 256, 0, stream>>>(x, ws32, cand, cap, kptr);   // guarded no-op
    k_filter<<<256, 256, 0, stream>>>(ws32, cand, cand2, out, cap, kptr);
    k_select<<<1, 256, 0, stream>>>(ws32, cand2, out, kptr);
}

// Round 15
// 114.725 us; speedup vs baseline: 1.5007x; 1.5007x over previous
//
#include <hip/hip_runtime.h>

// BatchTopK: relu(x), keep global top (k*1024) of 1024*24576 fp32, zero rest.
// Exact radix-select on positive-fp32 bit patterns + index-ordered tie-break.
//
// R15: R14 structure (5 launches; pick folded into k_main, scan folded into
// k_filter/k_select as redundant deterministic recompute — R14 showed
// prep/fb/filter/gaps ~1us each) with k_select FIXED: R14 ran it at 1 block
// x 256 threads with 4 passes -> 104us latency-bound (VALUBusy 0.015%).
// Now: 1024 threads, single cand2 pass, exact O(c^2) rank-count selection
// among the ~dozen cutoff-sub-bucket elements (hist fallback for c>2048).

#define N_ELEM   25165824            // 1024 * 24576
#define NV       (N_ELEM / 4)        // float4 count = 6291456 = 2048*256*12
#define HIST_SIZE 4096               // top-12-bit buckets
#define HREP     4                   // hist replicas
#define SREP     8                   // sample blocks / private replicas
#define NS       (NV / 256)          // sampled float4 count (1/256) = 24576
#define LCAP     1024                // per-block LDS candidate buffer
#define LCAP2    1024
#define SELCAP   2048
#define CAND2_CAP 262144
#define CAND_CAP  8388608

typedef float f32x4 __attribute__((ext_vector_type(4)));

// ws layout (uint32 words):
#define H_OFF     0                            // 4 x 4096 main hist (bits >= F)
#define H2_OFF    (H_OFF + HREP * HIST_SIZE)   // 16384: 4 x 4096 level-2 hist
#define HS_OFF    (H2_OFF + HREP * HIST_SIZE)  // 32768: 8 x 4096 sample replicas
#define META_OFF  (HS_OFF + SREP * HIST_SIZE)  // 65536: 32 words
#define CAND2_OFF (META_OFF + 32)              // 65568 (even -> uint2 ok)
#define CAND_OFF  (CAND2_OFF + 2 * CAND2_CAP)  // 589856 (even)
// meta: [0]=cand cnt  [7]=cand2 cnt   (cutoff params recomputed per block)

// K1 (8 blocks): zero H+H2+meta; 1/256 sample -> private replica.
__global__ void k_prep(const float4* __restrict__ x, unsigned* __restrict__ ws) {
    __shared__ unsigned lh[HIST_SIZE];
    for (int i = threadIdx.x; i < HIST_SIZE; i += 256) lh[i] = 0u;
    int gid = blockIdx.x * 256 + threadIdx.x;
    for (int i = gid; i < HS_OFF; i += SREP * 256) ws[i] = 0u;   // zero H + H2
    if (gid < 32) ws[META_OFF + gid] = 0u;
    __syncthreads();
    for (int s = gid; s < NS; s += SREP * 256) {
        int c = s >> 6, l = s & 63;          // 64 consecutive f4 per 16384-f4 chunk
        float4 v = x[c * 16384 + l];
        if (v.x > 0.0f) atomicAdd(&lh[__float_as_uint(v.x) >> 20], 1u);
        if (v.y > 0.0f) atomicAdd(&lh[__float_as_uint(v.y) >> 20], 1u);
        if (v.z > 0.0f) atomicAdd(&lh[__float_as_uint(v.z) >> 20], 1u);
        if (v.w > 0.0f) atomicAdd(&lh[__float_as_uint(v.w) >> 20], 1u);
    }
    __syncthreads();
    unsigned* hs = ws + HS_OFF + blockIdx.x * HIST_SIZE;
    for (int i = threadIdx.x; i < HIST_SIZE; i += 256) hs[i] = lh[i];
}

__device__ __forceinline__ void cand_push(unsigned b, unsigned idx,
                                          unsigned* lcnt, uint2* lc,
                                          unsigned* gcnt, uint2* cand, unsigned cap,
                                          unsigned* gh) {
    unsigned p = atomicAdd(lcnt, 1u);
    if (p < LCAP) lc[p] = make_uint2(b, idx);
    else {                                    // spill (~never): keep hist exact
        unsigned q = atomicAdd(gcnt, 1u);
        if (q < cap) { cand[q] = make_uint2(b, idx); atomicAdd(&gh[b >> 20], 1u); }
    }
}

// K2 (2048 x 256): per-block F pick (redundant, deterministic) + fused
// single-pass stream: {load f4, NT-store zero, compact >= F} x4-wide groups.
// Epilogue: block-local packed-u16 candidate histogram + single atomic flush.
__global__ __launch_bounds__(256) void k_main(const float4* __restrict__ x,
                                              float4* __restrict__ out,
                                              unsigned* __restrict__ ws,
                                              uint2* __restrict__ cand, unsigned cap,
                                              const int* __restrict__ kptr) {
    __shared__ unsigned pool[4096];          // phase A: sample hist; B: lc+lhp
    __shared__ unsigned ps[256];
    __shared__ unsigned F_sh, lcnt, gbase;
    const int t = threadIdx.x;
    // --- phase A: F = highest bucket with sampled suffix >= nk/128 ---
    for (int i = t; i < HIST_SIZE; i += 256) {
        unsigned s = 0u;
        #pragma unroll
        for (int r = 0; r < SREP; ++r) s += ws[HS_OFF + r * HIST_SIZE + i];
        pool[i] = s;
    }
    if (t == 0) F_sh = 1u;
    __syncthreads();
    unsigned nk = (unsigned)(*kptr) * 1024u;
    unsigned thr = nk / 128u; if (thr < 1u) thr = 1u;
    unsigned chunk = 0u;
    #pragma unroll
    for (int j = 0; j < 16; ++j) chunk += pool[t * 16 + j];
    ps[t] = chunk;
    __syncthreads();
    for (int st = 1; st < 256; st <<= 1) {
        unsigned v = (t + st < 256) ? ps[t + st] : 0u;
        __syncthreads();
        ps[t] += v;
        __syncthreads();
    }
    if (ps[0] >= thr) {
        unsigned S = (t < 255) ? ps[t + 1] : 0u;
        for (int j = 15; j >= 0; --j) {
            int b = t * 16 + j;
            unsigned Sb = S + pool[b];
            if (Sb >= thr && S < thr) F_sh = ((unsigned)b) << 20;
            S = Sb;
        }
    }
    __syncthreads();
    const unsigned F = F_sh;
    // --- phase B: stream; pool reused as lc[1024] (uint2) + lhp[2048] ---
    uint2* lc = reinterpret_cast<uint2*>(pool);
    unsigned* lhp = pool + 2048;
    if (t == 0) lcnt = 0u;
    for (int i = t; i < 2048; i += 256) lhp[i] = 0u;
    __syncthreads();
    unsigned* meta = ws + META_OFF;
    unsigned* gcnt = &meta[0];
    unsigned* gh = ws + H_OFF + (blockIdx.x & (HREP - 1)) * HIST_SIZE;
    const f32x4 z = {0.f, 0.f, 0.f, 0.f};
    int tid = blockIdx.x * 256 + t;
    const int stride = 2048 * 256;
    #pragma unroll
    for (int j = 0; j < 12; j += 4) {
        int i0 = tid + (j + 0) * stride;
        int i1 = tid + (j + 1) * stride;
        int i2 = tid + (j + 2) * stride;
        int i3 = tid + (j + 3) * stride;
        float4 v0 = x[i0];
        float4 v1 = x[i1];
        float4 v2 = x[i2];
        float4 v3 = x[i3];
        __builtin_nontemporal_store(z, (f32x4*)&out[i0]);
        __builtin_nontemporal_store(z, (f32x4*)&out[i1]);
        __builtin_nontemporal_store(z, (f32x4*)&out[i2]);
        __builtin_nontemporal_store(z, (f32x4*)&out[i3]);
        #pragma unroll
        for (int q = 0; q < 4; ++q) {
            float4 v = (q == 0) ? v0 : (q == 1) ? v1 : (q == 2) ? v2 : v3;
            int ii = (q == 0) ? i0 : (q == 1) ? i1 : (q == 2) ? i2 : i3;
            unsigned base = (unsigned)ii * 4u;
            unsigned b;
            b = __float_as_uint(fmaxf(v.x, 0.f)); if (b >= F) cand_push(b, base + 0u, &lcnt, lc, gcnt, cand, cap, gh);
            b = __float_as_uint(fmaxf(v.y, 0.f)); if (b >= F) cand_push(b, base + 1u, &lcnt, lc, gcnt, cand, cap, gh);
            b = __float_as_uint(fmaxf(v.z, 0.f)); if (b >= F) cand_push(b, base + 2u, &lcnt, lc, gcnt, cand, cap, gh);
            b = __float_as_uint(fmaxf(v.w, 0.f)); if (b >= F) cand_push(b, base + 3u, &lcnt, lc, gcnt, cand, cap, gh);
        }
    }
    __syncthreads();
    unsigned n = lcnt < LCAP ? lcnt : LCAP;
    for (unsigned e = t; e < n; e += 256) {
        unsigned b12 = lc[e].x >> 20;
        atomicAdd(&lhp[b12 >> 1], 1u << ((b12 & 1u) * 16u));
    }
    __syncthreads();
    if (t == 0 && n) gbase = atomicAdd(gcnt, n);
    __syncthreads();
    for (unsigned e = t; e < n; e += 256) {
        unsigned q = gbase + e;
        if (q < cap) cand[q] = lc[e];
    }
    for (int i = t; i < 2048; i += 256) {
        unsigned w = lhp[i];
        if (w & 0xFFFFu) atomicAdd(&gh[i * 2],     w & 0xFFFFu);
        if (w >> 16)     atomicAdd(&gh[i * 2 + 1], w >> 16);
    }
}

// K3 (2048, self-guarded): meta[0] == exact count(bits>=F). If >= nk, floor
// held -> no-op. Else complement pass (0 < bits < F) restores exactness.
__global__ void k_fb(const float4* __restrict__ x, unsigned* __restrict__ ws,
                     uint2* __restrict__ cand, unsigned cap,
                     const int* __restrict__ kptr) {
    unsigned* meta = ws + META_OFF;
    unsigned nk = (unsigned)(*kptr) * 1024u;
    if (meta[0] >= nk) return;               // floor held (normal path)
    __shared__ uint2 lc[LCAP];
    __shared__ unsigned lhp[HIST_SIZE / 2];
    __shared__ unsigned lcnt, gbase;
    if (threadIdx.x == 0) lcnt = 0u;
    for (int i = threadIdx.x; i < HIST_SIZE / 2; i += blockDim.x) lhp[i] = 0u;
    __syncthreads();
    // F recomputed the same way k_main did (deterministic).
    __shared__ unsigned pool2[4096];
    __shared__ unsigned ps[256];
    __shared__ unsigned F_sh;
    const int t = threadIdx.x;
    for (int i = t; i < HIST_SIZE; i += 256) {
        unsigned s = 0u;
        #pragma unroll
        for (int r = 0; r < SREP; ++r) s += ws[HS_OFF + r * HIST_SIZE + i];
        pool2[i] = s;
    }
    if (t == 0) F_sh = 1u;
    __syncthreads();
    unsigned thr = nk / 128u; if (thr < 1u) thr = 1u;
    unsigned chunk = 0u;
    #pragma unroll
    for (int j = 0; j < 16; ++j) chunk += pool2[t * 16 + j];
    ps[t] = chunk;
    __syncthreads();
    for (int st = 1; st < 256; st <<= 1) {
        unsigned v = (t + st < 256) ? ps[t + st] : 0u;
        __syncthreads();
        ps[t] += v;
        __syncthreads();
    }
    if (ps[0] >= thr) {
        unsigned S = (t < 255) ? ps[t + 1] : 0u;
        for (int j = 15; j >= 0; --j) {
            int b = t * 16 + j;
            unsigned Sb = S + pool2[b];
            if (Sb >= thr && S < thr) F_sh = ((unsigned)b) << 20;
            S = Sb;
        }
    }
    __syncthreads();
    const unsigned F = F_sh;
    unsigned* gcnt = &meta[0];
    unsigned* gh = ws + H_OFF + (blockIdx.x & (HREP - 1)) * HIST_SIZE;
    int stride = gridDim.x * blockDim.x;
    for (int i = blockIdx.x * blockDim.x + threadIdx.x; i < NV; i += stride) {
        float4 v = x[i];
        unsigned base = (unsigned)i * 4u;
        #pragma unroll
        for (int c = 0; c < 4; ++c) {
            float a = (c == 0) ? v.x : (c == 1) ? v.y : (c == 2) ? v.z : v.w;
            unsigned b = __float_as_uint(fmaxf(a, 0.f));
            if (b >= 1u && b < F) cand_push(b, base + (unsigned)c, &lcnt, lc, gcnt, cand, cap, gh);
        }
    }
    __syncthreads();
    unsigned n = lcnt < LCAP ? lcnt : LCAP;
    for (unsigned e = threadIdx.x; e < n; e += blockDim.x) {
        unsigned b12 = lc[e].x >> 20;
        atomicAdd(&lhp[b12 >> 1], 1u << ((b12 & 1u) * 16u));
    }
    __syncthreads();
    if (threadIdx.x == 0 && n) gbase = atomicAdd(gcnt, n);
    __syncthreads();
    for (unsigned e = threadIdx.x; e < n; e += blockDim.x) {
        unsigned q = gbase + e;
        if (q < cap) cand[q] = lc[e];
    }
    for (int i = threadIdx.x; i < HIST_SIZE / 2; i += blockDim.x) {
        unsigned w = lhp[i];
        if (w & 0xFFFFu) atomicAdd(&gh[i * 2],     w & 0xFFFFu);
        if (w >> 16)     atomicAdd(&gh[i * 2 + 1], w >> 16);
    }
}

// K4 (256 x 256): per-block scan of H (redundant) -> b12/c_above/keepall;
// scatter definite keepers (bucket > b12); compact ==b12 -> cand2 + H2.
__global__ __launch_bounds__(256) void k_filter(unsigned* __restrict__ ws,
                                                const uint2* __restrict__ cand,
                                                uint2* __restrict__ cand2,
                                                float* __restrict__ out, unsigned cap,
                                                const int* __restrict__ kptr) {
    __shared__ unsigned pool[4096];          // scan buf, then lc2[1024] (uint2)
    __shared__ unsigned ps[256];
    __shared__ unsigned b12_sh, lcnt, gbase;
    const int t = threadIdx.x;
    unsigned* meta = ws + META_OFF;
    unsigned nk = (unsigned)(*kptr) * 1024u;
    for (int i = t; i < HIST_SIZE; i += 256) {
        unsigned s = 0u;
        #pragma unroll
        for (int r = 0; r < HREP; ++r) s += ws[H_OFF + r * HIST_SIZE + i];
        pool[i] = s;
    }
    if (t == 0) lcnt = 0u;
    __syncthreads();
    unsigned chunk = 0u;
    #pragma unroll
    for (int j = 0; j < 16; ++j) chunk += pool[t * 16 + j];
    ps[t] = chunk;
    __syncthreads();
    for (int st = 1; st < 256; st <<= 1) {
        unsigned v = (t + st < 256) ? ps[t + st] : 0u;
        __syncthreads();
        ps[t] += v;
        __syncthreads();
    }
    unsigned total = ps[0];
    unsigned keepall = (total < nk) ? 1u : 0u;
    if (!keepall) {
        unsigned S = (t < 255) ? ps[t + 1] : 0u;
        for (int j = 15; j >= 0; --j) {
            int b = t * 16 + j;
            unsigned Sb = S + pool[b];
            if (Sb >= nk && S < nk) b12_sh = (unsigned)b;
            S = Sb;
        }
    }
    __syncthreads();
    unsigned ncand = meta[0]; if (ncand > cap) ncand = cap;
    unsigned stride = gridDim.x * blockDim.x;
    if (keepall) {
        for (unsigned i = blockIdx.x * blockDim.x + t; i < ncand; i += stride) {
            uint2 c = cand[i];
            out[c.y] = __uint_as_float(c.x);
        }
        return;
    }
    unsigned b12 = b12_sh;
    uint2* lc2 = reinterpret_cast<uint2*>(pool);    // scan data dead now
    unsigned* h2 = ws + H2_OFF + (blockIdx.x & (HREP - 1)) * HIST_SIZE;
    unsigned* cnt2 = &meta[7];
    for (unsigned i = blockIdx.x * blockDim.x + t; i < ncand; i += stride) {
        uint2 c = cand[i];
        unsigned bk = c.x >> 20;
        if (bk > b12) {
            out[c.y] = __uint_as_float(c.x);        // definite keeper
        } else if (bk == b12) {
            atomicAdd(&h2[(c.x >> 8) & 0xFFFu], 1u);
            unsigned p = atomicAdd(&lcnt, 1u);
            if (p < LCAP2) lc2[p] = c;
            else { unsigned q = atomicAdd(cnt2, 1u); if (q < CAND2_CAP) cand2[q] = c; }
        }
    }
    __syncthreads();
    unsigned n = lcnt < LCAP2 ? lcnt : LCAP2;
    if (t == 0 && n) gbase = atomicAdd(cnt2, n);
    __syncthreads();
    for (unsigned e = t; e < n; e += 256) {
        unsigned q = gbase + e;
        if (q < CAND2_CAP) cand2[q] = lc2[e];
    }
}

// K5 (1 block x 1024): recompute b12/c_above + s2/ca2 from hist replicas;
// ONE pass over cand2 (sub>s2 -> scatter; ==s2 -> LDS collect); exact O(c^2)
// rank-count selection among collected (value desc, index asc = jax order).
// Histogram fallback only if the sub-bucket holds > SELCAP elements.
__global__ __launch_bounds__(1024) void k_select(unsigned* __restrict__ ws,
                                                 const uint2* __restrict__ cand2,
                                                 float* __restrict__ out,
                                                 const int* __restrict__ kptr) {
    __shared__ unsigned h[HIST_SIZE];
    __shared__ unsigned ps[1024];
    __shared__ uint2 sel[SELCAP];
    __shared__ unsigned h3[256];
    __shared__ unsigned selcnt, b12_sh, ca_sh, s2_sh, ca2_sh, t3_sh, ca3_sh;
    const int t = threadIdx.x;
    unsigned* meta = ws + META_OFF;
    unsigned nk = (unsigned)(*kptr) * 1024u;
    // --- scan H -> b12, ca (keepall handled by k_filter) ---
    for (int i = t; i < HIST_SIZE; i += 1024) {
        unsigned s = 0u;
        #pragma unroll
        for (int r = 0; r < HREP; ++r) s += ws[H_OFF + r * HIST_SIZE + i];
        h[i] = s;
    }
    if (t == 0) selcnt = 0u;
    if (t < 256) h3[t] = 0u;
    __syncthreads();
    unsigned chunk = h[t*4] + h[t*4+1] + h[t*4+2] + h[t*4+3];
    ps[t] = chunk;
    __syncthreads();
    for (int st = 1; st < 1024; st <<= 1) {
        unsigned v = (t + st < 1024) ? ps[t + st] : 0u;
        __syncthreads();
        ps[t] += v;
        __syncthreads();
    }
    if (ps[0] < nk) return;                  // keepall: k_filter scattered all
    {
        unsigned S = (t < 1023) ? ps[t + 1] : 0u;
        for (int j = 3; j >= 0; --j) {
            int b = t * 4 + j;
            unsigned Sb = S + h[b];
            if (Sb >= nk && S < nk) { b12_sh = (unsigned)b; ca_sh = S; }
            S = Sb;
        }
    }
    __syncthreads();
    unsigned b12 = b12_sh;
    unsigned m = nk - ca_sh;                 // rank within bucket b12, >=1
    unsigned n2 = meta[7]; if (n2 > CAND2_CAP) n2 = CAND2_CAP;
    // --- scan H2 -> s2, ca2 at rank m ---
    for (int i = t; i < HIST_SIZE; i += 1024) {
        unsigned s = 0u;
        #pragma unroll
        for (int r = 0; r < HREP; ++r) s += ws[H2_OFF + r * HIST_SIZE + i];
        h[i] = s;
    }
    __syncthreads();
    chunk = h[t*4] + h[t*4+1] + h[t*4+2] + h[t*4+3];
    ps[t] = chunk;
    __syncthreads();
    for (int st = 1; st < 1024; st <<= 1) {
        unsigned v = (t + st < 1024) ? ps[t + st] : 0u;
        __syncthreads();
        ps[t] += v;
        __syncthreads();
    }
    {
        unsigned S = (t < 1023) ? ps[t + 1] : 0u;
        for (int j = 3; j >= 0; --j) {
            int b = t * 4 + j;
            unsigned Sb = S + h[b];
            if (Sb >= m && S < m) { s2_sh = (unsigned)b; ca2_sh = S; }
            S = Sb;
        }
    }
    __syncthreads();
    unsigned s2 = s2_sh;
    unsigned m2 = m - ca2_sh;                // rank within sub-bucket, >=1
    // --- single pass over cand2: scatter sub>s2, collect sub==s2 ---
    for (unsigned i = t; i < n2; i += 1024) {
        uint2 c = cand2[i];
        if ((c.x >> 20) != b12) continue;    // (cand2 only holds b12, cheap guard)
        unsigned sub = (c.x >> 8) & 0xFFFu;
        if (sub > s2) {
            out[c.y] = __uint_as_float(c.x);
        } else if (sub == s2) {
            unsigned p = atomicAdd(&selcnt, 1u);
            if (p < SELCAP) sel[p] = c;
        }
    }
    __syncthreads();
    unsigned c_all = selcnt;
    if (c_all <= SELCAP) {
        // --- exact O(c^2) rank-count: keep if (#greater + #equal-with-lower-idx) < m2 ---
        unsigned cc = c_all;
        for (unsigned e = t; e < cc; e += 1024) {
            uint2 me = sel[e];
            unsigned rank = 0u;
            for (unsigned j = 0; j < cc; ++j) {
                uint2 o = sel[j];
                rank += (o.x > me.x || (o.x == me.x && o.y < me.y)) ? 1u : 0u;
            }
            if (rank < m2) out[me.y] = __uint_as_float(me.x);
        }
        return;
    }
    // --- fallback (degenerate: >SELCAP elems share sub-bucket): h3 path ---
    for (unsigned i = t; i < n2; i += 1024) {
        uint2 c = cand2[i];
        if (((c.x >> 8) & 0xFFFu) == s2 && (c.x >> 20) == b12)
            atomicAdd(&h3[c.x & 0xFFu], 1u);
    }
    __syncthreads();
    if (t < 256) ps[t] = h3[t];
    __syncthreads();
    for (int st = 1; st < 256; st <<= 1) {
        unsigned v = 0u;
        if (t < 256) v = (t + st < 256) ? ps[t + st] : 0u;
        __syncthreads();
        if (t < 256) ps[t] += v;
        __syncthreads();
    }
    if (t < 256) {
        unsigned S3 = (t < 255) ? ps[t + 1] : 0u;
        unsigned Sb = S3 + h3[t];
        if (Sb >= m2 && S3 < m2) { t3_sh = (unsigned)t; ca3_sh = S3; }
    }
    if (t == 0) selcnt = 0u;
    __syncthreads();
    unsigned tau = (b12 << 20) | (s2 << 8) | t3_sh;
    unsigned r = m2 - ca3_sh;                // exact-tie keepers
    for (unsigned i = t; i < n2; i += 1024) {
        uint2 c = cand2[i];
        if ((c.x >> 20) != b12 || ((c.x >> 8) & 0xFFFu) != s2) continue;
        if (c.x > tau) {
            out[c.y] = __uint_as_float(c.x);
        } else if (c.x == tau) {
            unsigned q = atomicAdd(&selcnt, 1u);
            if (q < SELCAP) sel[q] = c;
        }
    }
    __syncthreads();
    unsigned tc = selcnt; if (tc > SELCAP) tc = SELCAP;
    float tv = __uint_as_float(tau);
    for (unsigned e = t; e < tc; e += 1024) {
        uint2 me = sel[e];
        unsigned rank = 0u;
        for (unsigned j = 0; j < tc; ++j) rank += (sel[j].y < me.y) ? 1u : 0u;
        if (rank < r) out[me.y] = tv;        // keep r lowest-index ties
    }
}

extern "C" void kernel_launch(void* const* d_in, const int* in_sizes, int n_in,
                              void* d_out, int out_size, void* d_ws, size_t ws_size,
                              hipStream_t stream) {
    const float4* x = (const float4*)d_in[0];
    const int* kptr = (const int*)d_in[1];
    float* out = (float*)d_out;
    unsigned* ws32 = (unsigned*)d_ws;
    uint2* cand2 = (uint2*)(ws32 + CAND2_OFF);
    uint2* cand  = (uint2*)(ws32 + CAND_OFF);

    unsigned cap = CAND_CAP;
    size_t hdr = (size_t)CAND_OFF * 4;
    if (ws_size < hdr + (size_t)CAND_CAP * 8) {
        cap = (ws_size > hdr) ? (unsigned)((ws_size - hdr) / 8) : 0u;
    }

    k_prep<<<SREP, 256, 0, stream>>>(x, ws32);
    k_main<<<2048, 256, 0, stream>>>(x, (float4*)out, ws32, cand, cap, kptr);
    k_fb<<<2048, 256, 0, stream>>>(x, ws32, cand, cap, kptr);   // guarded no-op
    k_filter<<<256, 256, 0, stream>>>(ws32, cand, cand2, out, cap, kptr);
    k_select<<<1, 1024, 0, stream>>>(ws32, cand2, out, kptr);
}

// Round 16
// 83.733 us; speedup vs baseline: 2.0561x; 1.3701x over previous
//
#include <hip/hip_runtime.h>

// BatchTopK: relu(x), keep global top (k*1024) of 1024*24576 fp32, zero rest.
// Exact radix-select on positive-fp32 bit patterns + index-ordered tie-break.
//
// R16: all histogram scans register-based (R15's pool[t*16+j] chunk-sum was a
// 32-way LDS bank conflict: 4.45M conflict cycles, k_main 63->72us). Single
// summed hist_s (separate k_zero kernel avoids the zero/atomic race) so
// k_main's F-pick reads 16KB not 128KB. Select split into 256-block sel_a
// (scatter + collect ~dozens of cutoff-sub-bucket elems) + 1-block sel_b
// (exact O(c^2) value-desc/index-asc rank count) — R14/R15 showed 1-block
// kernels pay ~900cyc/load on cross-XCD data, so sel_b reads only a few KB.

#define N_ELEM   25165824            // 1024 * 24576
#define NV       (N_ELEM / 4)        // float4 count = 6291456 = 2048*256*12
#define HIST_SIZE 4096               // top-12-bit buckets
#define HREP     4                   // hist replicas
#define NS       (NV / 256)          // sampled float4 count (1/256) = 24576
#define LCAP     1024                // per-block LDS candidate buffer
#define LCAP2    1024
#define SELCAP   4096
#define CAND2_CAP 262144
#define CAND_CAP  8388608

typedef float f32x4 __attribute__((ext_vector_type(4)));

// ws layout (uint32 words):
#define H_OFF     0                            // 4 x 4096 main hist (bits >= F)
#define H2_OFF    (H_OFF + HREP * HIST_SIZE)   // 16384: 4 x 4096 level-2 hist
#define HS_OFF    (H2_OFF + HREP * HIST_SIZE)  // 32768: single summed sample hist
#define META_OFF  (HS_OFF + HIST_SIZE)         // 36864: 32 words
#define SEL_OFF   (META_OFF + 32)              // 36896 (even): sel, uint2 x SELCAP
#define CAND2_OFF (SEL_OFF + 2 * SELCAP)       // 45088 (even)
#define CAND_OFF  (CAND2_OFF + 2 * CAND2_CAP)  // 569376 (even)
#define ZERO_WORDS (META_OFF + 32)
// meta: [0]=cand cnt  [7]=cand2 cnt  [9]=sel cnt

// Register-based rank scan over a (replicated) 4096-bucket histogram.
// 256 threads; thread t owns buckets [t*16, t*16+16) in 16 VGPRs; LDS only
// for the conflict-free 256-entry suffix scan. Returns total; picked[0]=bucket
// containing rank, picked[1]=count strictly above it (set only if total>=rank).
__device__ __forceinline__ unsigned scan_pick256(const unsigned* __restrict__ base,
                                                 int nrep, unsigned rank,
                                                 unsigned* ps, unsigned* picked) {
    const int t = threadIdx.x;
    unsigned hv[16];
    #pragma unroll
    for (int j = 0; j < 16; ++j) {
        unsigned s = 0u;
        for (int r = 0; r < nrep; ++r) s += base[r * HIST_SIZE + t * 16 + j];
        hv[j] = s;
    }
    unsigned chunk = 0u;
    #pragma unroll
    for (int j = 0; j < 16; ++j) chunk += hv[j];
    __syncthreads();                 // guard ps reuse across calls
    ps[t] = chunk;
    __syncthreads();
    for (int st = 1; st < 256; st <<= 1) {
        unsigned v = (t + st < 256) ? ps[t + st] : 0u;
        __syncthreads();
        ps[t] += v;
        __syncthreads();
    }
    unsigned total = ps[0];
    if (total >= rank) {
        unsigned S = (t < 255) ? ps[t + 1] : 0u;
        #pragma unroll
        for (int j = 15; j >= 0; --j) {
            int b = t * 16 + j;
            unsigned Sb = S + hv[j];
            if (Sb >= rank && S < rank) { picked[0] = (unsigned)b; picked[1] = S; }
            S = Sb;
        }
    }
    __syncthreads();
    return total;
}

// K0 (64 blocks): zero H + H2 + hist_s + meta.
__global__ void k_zero(unsigned* __restrict__ ws) {
    for (int i = blockIdx.x * 256 + threadIdx.x; i < ZERO_WORDS; i += 64 * 256)
        ws[i] = 0u;
}

// K1 (8 blocks): 1/256 sample -> atomic flush into single hist_s.
__global__ void k_sample(const float4* __restrict__ x, unsigned* __restrict__ ws) {
    __shared__ unsigned lh[HIST_SIZE];
    for (int i = threadIdx.x; i < HIST_SIZE; i += 256) lh[i] = 0u;
    __syncthreads();
    int gid = blockIdx.x * 256 + threadIdx.x;
    for (int s = gid; s < NS; s += 8 * 256) {
        int c = s >> 6, l = s & 63;          // 64 consecutive f4 per 16384-f4 chunk
        float4 v = x[c * 16384 + l];
        if (v.x > 0.0f) atomicAdd(&lh[__float_as_uint(v.x) >> 20], 1u);
        if (v.y > 0.0f) atomicAdd(&lh[__float_as_uint(v.y) >> 20], 1u);
        if (v.z > 0.0f) atomicAdd(&lh[__float_as_uint(v.z) >> 20], 1u);
        if (v.w > 0.0f) atomicAdd(&lh[__float_as_uint(v.w) >> 20], 1u);
    }
    __syncthreads();
    unsigned* hs = ws + HS_OFF;
    for (int i = threadIdx.x; i < HIST_SIZE; i += 256)
        if (lh[i]) atomicAdd(&hs[i], lh[i]);
}

__device__ __forceinline__ void cand_push(unsigned b, unsigned idx,
                                          unsigned* lcnt, uint2* lc,
                                          unsigned* gcnt, uint2* cand, unsigned cap,
                                          unsigned* gh) {
    unsigned p = atomicAdd(lcnt, 1u);
    if (p < LCAP) lc[p] = make_uint2(b, idx);
    else {                                    // spill (~never): keep hist exact
        unsigned q = atomicAdd(gcnt, 1u);
        if (q < cap) { cand[q] = make_uint2(b, idx); atomicAdd(&gh[b >> 20], 1u); }
    }
}

// K2 (2048 x 256): register-based F pick (16 L2-hot loads) + fused stream:
// {load f4, NT-store zero, compact >= F} x4-wide groups (R5/R13 shape,
// fastest measured). Epilogue: packed-u16 block hist + single atomic flush.
__global__ __launch_bounds__(256) void k_main(const float4* __restrict__ x,
                                              float4* __restrict__ out,
                                              unsigned* __restrict__ ws,
                                              uint2* __restrict__ cand, unsigned cap,
                                              const int* __restrict__ kptr) {
    __shared__ unsigned pool[4096];          // lc[1024] (uint2) + lhp[2048]
    __shared__ unsigned ps[256];
    __shared__ unsigned picked[2];
    __shared__ unsigned lcnt, gbase;
    const int t = threadIdx.x;
    unsigned nk = (unsigned)(*kptr) * 1024u;
    unsigned thr = nk / 128u; if (thr < 1u) thr = 1u;
    unsigned total_s = scan_pick256(ws + HS_OFF, 1, thr, ps, picked);
    const unsigned F = (total_s >= thr) ? (picked[0] << 20) : 1u;
    uint2* lc = reinterpret_cast<uint2*>(pool);
    unsigned* lhp = pool + 2048;
    if (t == 0) lcnt = 0u;
    for (int i = t; i < 2048; i += 256) lhp[i] = 0u;
    __syncthreads();
    unsigned* meta = ws + META_OFF;
    unsigned* gcnt = &meta[0];
    unsigned* gh = ws + H_OFF + (blockIdx.x & (HREP - 1)) * HIST_SIZE;
    const f32x4 z = {0.f, 0.f, 0.f, 0.f};
    int tid = blockIdx.x * 256 + t;
    const int stride = 2048 * 256;
    #pragma unroll
    for (int j = 0; j < 12; j += 4) {
        int i0 = tid + (j + 0) * stride;
        int i1 = tid + (j + 1) * stride;
        int i2 = tid + (j + 2) * stride;
        int i3 = tid + (j + 3) * stride;
        float4 v0 = x[i0];
        float4 v1 = x[i1];
        float4 v2 = x[i2];
        float4 v3 = x[i3];
        __builtin_nontemporal_store(z, (f32x4*)&out[i0]);
        __builtin_nontemporal_store(z, (f32x4*)&out[i1]);
        __builtin_nontemporal_store(z, (f32x4*)&out[i2]);
        __builtin_nontemporal_store(z, (f32x4*)&out[i3]);
        #pragma unroll
        for (int q = 0; q < 4; ++q) {
            float4 v = (q == 0) ? v0 : (q == 1) ? v1 : (q == 2) ? v2 : v3;
            int ii = (q == 0) ? i0 : (q == 1) ? i1 : (q == 2) ? i2 : i3;
            unsigned base = (unsigned)ii * 4u;
            unsigned b;
            b = __float_as_uint(fmaxf(v.x, 0.f)); if (b >= F) cand_push(b, base + 0u, &lcnt, lc, gcnt, cand, cap, gh);
            b = __float_as_uint(fmaxf(v.y, 0.f)); if (b >= F) cand_push(b, base + 1u, &lcnt, lc, gcnt, cand, cap, gh);
            b = __float_as_uint(fmaxf(v.z, 0.f)); if (b >= F) cand_push(b, base + 2u, &lcnt, lc, gcnt, cand, cap, gh);
            b = __float_as_uint(fmaxf(v.w, 0.f)); if (b >= F) cand_push(b, base + 3u, &lcnt, lc, gcnt, cand, cap, gh);
        }
    }
    __syncthreads();
    unsigned n = lcnt < LCAP ? lcnt : LCAP;
    for (unsigned e = t; e < n; e += 256) {
        unsigned b12 = lc[e].x >> 20;
        atomicAdd(&lhp[b12 >> 1], 1u << ((b12 & 1u) * 16u));
    }
    __syncthreads();
    if (t == 0 && n) gbase = atomicAdd(gcnt, n);
    __syncthreads();
    for (unsigned e = t; e < n; e += 256) {
        unsigned q = gbase + e;
        if (q < cap) cand[q] = lc[e];
    }
    for (int i = t; i < 2048; i += 256) {
        unsigned w = lhp[i];
        if (w & 0xFFFFu) atomicAdd(&gh[i * 2],     w & 0xFFFFu);
        if (w >> 16)     atomicAdd(&gh[i * 2 + 1], w >> 16);
    }
}

// K3 (2048, self-guarded): meta[0] == exact count(bits>=F). If >= nk, floor
// held -> no-op. Else complement pass (0 < bits < F) restores exactness.
__global__ __launch_bounds__(256) void k_fb(const float4* __restrict__ x,
                                            unsigned* __restrict__ ws,
                                            uint2* __restrict__ cand, unsigned cap,
                                            const int* __restrict__ kptr) {
    unsigned* meta = ws + META_OFF;
    unsigned nk = (unsigned)(*kptr) * 1024u;
    if (meta[0] >= nk) return;               // floor held (normal path)
    __shared__ unsigned pool[4096];          // lc[1024] (uint2) + lhp[2048]
    __shared__ unsigned ps[256];
    __shared__ unsigned picked[2];
    __shared__ unsigned lcnt, gbase;
    const int t = threadIdx.x;
    unsigned thr = nk / 128u; if (thr < 1u) thr = 1u;
    unsigned total_s = scan_pick256(ws + HS_OFF, 1, thr, ps, picked);
    const unsigned F = (total_s >= thr) ? (picked[0] << 20) : 1u;
    uint2* lc = reinterpret_cast<uint2*>(pool);
    unsigned* lhp = pool + 2048;
    if (t == 0) lcnt = 0u;
    for (int i = t; i < 2048; i += 256) lhp[i] = 0u;
    __syncthreads();
    unsigned* gcnt = &meta[0];
    unsigned* gh = ws + H_OFF + (blockIdx.x & (HREP - 1)) * HIST_SIZE;
    int stride = gridDim.x * blockDim.x;
    for (int i = blockIdx.x * blockDim.x + t; i < NV; i += stride) {
        float4 v = x[i];
        unsigned base = (unsigned)i * 4u;
        #pragma unroll
        for (int c = 0; c < 4; ++c) {
            float a = (c == 0) ? v.x : (c == 1) ? v.y : (c == 2) ? v.z : v.w;
            unsigned b = __float_as_uint(fmaxf(a, 0.f));
            if (b >= 1u && b < F) cand_push(b, base + (unsigned)c, &lcnt, lc, gcnt, cand, cap, gh);
        }
    }
    __syncthreads();
    unsigned n = lcnt < LCAP ? lcnt : LCAP;
    for (unsigned e = t; e < n; e += 256) {
        unsigned b12 = lc[e].x >> 20;
        atomicAdd(&lhp[b12 >> 1], 1u << ((b12 & 1u) * 16u));
    }
    __syncthreads();
    if (t == 0 && n) gbase = atomicAdd(gcnt, n);
    __syncthreads();
    for (unsigned e = t; e < n; e += 256) {
        unsigned q = gbase + e;
        if (q < cap) cand[q] = lc[e];
    }
    for (int i = t; i < 2048; i += 256) {
        unsigned w = lhp[i];
        if (w & 0xFFFFu) atomicAdd(&gh[i * 2],     w & 0xFFFFu);
        if (w >> 16)     atomicAdd(&gh[i * 2 + 1], w >> 16);
    }
}

// K4 (256 x 256): register scan of H -> b12/keepall; scatter bucket>b12
// keepers; compact ==b12 -> cand2 + H2 replicas. keepall: scatter all.
__global__ __launch_bounds__(256) void k_filter(unsigned* __restrict__ ws,
                                                const uint2* __restrict__ cand,
                                                uint2* __restrict__ cand2,
                                                float* __restrict__ out, unsigned cap,
                                                const int* __restrict__ kptr) {
    __shared__ unsigned pool[2048];          // lc2[1024] (uint2)
    __shared__ unsigned ps[256];
    __shared__ unsigned picked[2];
    __shared__ unsigned lcnt, gbase;
    const int t = threadIdx.x;
    unsigned* meta = ws + META_OFF;
    unsigned nk = (unsigned)(*kptr) * 1024u;
    unsigned total = scan_pick256(ws + H_OFF, HREP, nk, ps, picked);
    unsigned keepall = (total < nk) ? 1u : 0u;
    if (t == 0) lcnt = 0u;
    __syncthreads();
    unsigned ncand = meta[0]; if (ncand > cap) ncand = cap;
    unsigned stride = gridDim.x * blockDim.x;
    if (keepall) {
        for (unsigned i = blockIdx.x * blockDim.x + t; i < ncand; i += stride) {
            uint2 c = cand[i];
            out[c.y] = __uint_as_float(c.x);
        }
        return;
    }
    unsigned b12 = picked[0];
    uint2* lc2 = reinterpret_cast<uint2*>(pool);
    unsigned* h2 = ws + H2_OFF + (blockIdx.x & (HREP - 1)) * HIST_SIZE;
    unsigned* cnt2 = &meta[7];
    for (unsigned i = blockIdx.x * blockDim.x + t; i < ncand; i += stride) {
        uint2 c = cand[i];
        unsigned bk = c.x >> 20;
        if (bk > b12) {
            out[c.y] = __uint_as_float(c.x);        // definite keeper
        } else if (bk == b12) {
            atomicAdd(&h2[(c.x >> 8) & 0xFFFu], 1u);
            unsigned p = atomicAdd(&lcnt, 1u);
            if (p < LCAP2) lc2[p] = c;
            else { unsigned q = atomicAdd(cnt2, 1u); if (q < CAND2_CAP) cand2[q] = c; }
        }
    }
    __syncthreads();
    unsigned n = lcnt < LCAP2 ? lcnt : LCAP2;
    if (t == 0 && n) gbase = atomicAdd(cnt2, n);
    __syncthreads();
    for (unsigned e = t; e < n; e += 256) {
        unsigned q = gbase + e;
        if (q < CAND2_CAP) cand2[q] = lc2[e];
    }
}

// K5 (256 x 256): register scans (H -> b12/ca, H2 -> s2) redundantly per
// block; pass over cand2: sub>s2 -> scatter, sub==s2 -> collect to global sel.
__global__ __launch_bounds__(256) void k_sel_a(unsigned* __restrict__ ws,
                                               const uint2* __restrict__ cand2,
                                               uint2* __restrict__ sel,
                                               float* __restrict__ out,
                                               const int* __restrict__ kptr) {
    __shared__ unsigned ps[256];
    __shared__ unsigned picked[2];
    const int t = threadIdx.x;
    unsigned* meta = ws + META_OFF;
    unsigned nk = (unsigned)(*kptr) * 1024u;
    unsigned total = scan_pick256(ws + H_OFF, HREP, nk, ps, picked);
    if (total < nk) return;                  // keepall: k_filter scattered all
    unsigned m = nk - picked[1];             // rank within bucket b12, >=1
    scan_pick256(ws + H2_OFF, HREP, m, ps, picked);
    unsigned s2 = picked[0];
    unsigned n2 = meta[7]; if (n2 > CAND2_CAP) n2 = CAND2_CAP;
    unsigned stride = gridDim.x * blockDim.x;
    for (unsigned i = blockIdx.x * blockDim.x + t; i < n2; i += stride) {
        uint2 c = cand2[i];
        unsigned sub = (c.x >> 8) & 0xFFFu;
        if (sub > s2) {
            out[c.y] = __uint_as_float(c.x);
        } else if (sub == s2) {
            unsigned q = atomicAdd(&meta[9], 1u);
            if (q < SELCAP) sel[q] = c;
        }
    }
}

// K6 (1 block x 256): recompute ranks; exact O(c^2) rank-count over the
// collected sub-bucket elements (value desc, index asc = jax order).
// Histogram fallback if the sub-bucket overflows SELCAP (degenerate ties).
__global__ __launch_bounds__(256) void k_sel_b(unsigned* __restrict__ ws,
                                               const uint2* __restrict__ cand2,
                                               const uint2* __restrict__ sel,
                                               float* __restrict__ out,
                                               const int* __restrict__ kptr) {
    __shared__ uint2 sel_l[SELCAP];          // 32 KB
    __shared__ unsigned ps[256];
    __shared__ unsigned picked[2];
    __shared__ unsigned h3[256];
    __shared__ unsigned t3_sh, ca3_sh, tie_cnt;
    const int t = threadIdx.x;
    unsigned* meta = ws + META_OFF;
    unsigned nk = (unsigned)(*kptr) * 1024u;
    unsigned total = scan_pick256(ws + H_OFF, HREP, nk, ps, picked);
    if (total < nk) return;                  // keepall handled earlier
    unsigned b12 = picked[0];
    unsigned m = nk - picked[1];
    scan_pick256(ws + H2_OFF, HREP, m, ps, picked);
    unsigned s2 = picked[0];
    unsigned m2 = m - picked[1];             // rank within sub-bucket, >=1
    unsigned cgot = meta[9];
    if (cgot <= SELCAP) {
        unsigned cc = cgot;
        for (unsigned i = t; i < cc; i += 256) sel_l[i] = sel[i];
        __syncthreads();
        for (unsigned e = t; e < cc; e += 256) {
            uint2 me = sel_l[e];
            unsigned rank = 0u;
            for (unsigned j = 0; j < cc; ++j) {
                uint2 o = sel_l[j];
                rank += (o.x > me.x || (o.x == me.x && o.y < me.y)) ? 1u : 0u;
            }
            if (rank < m2) out[me.y] = __uint_as_float(me.x);
        }
        return;
    }
    // --- fallback (degenerate: sub-bucket > SELCAP): h3 histogram path ---
    unsigned n2 = meta[7]; if (n2 > CAND2_CAP) n2 = CAND2_CAP;
    h3[t] = 0u;
    if (t == 0) tie_cnt = 0u;
    __syncthreads();
    for (unsigned i = t; i < n2; i += 256) {
        uint2 c = cand2[i];
        if (((c.x >> 8) & 0xFFFu) == s2) atomicAdd(&h3[c.x & 0xFFu], 1u);
    }
    __syncthreads();
    ps[t] = h3[t];
    __syncthreads();
    for (int st = 1; st < 256; st <<= 1) {
        unsigned v = (t + st < 256) ? ps[t + st] : 0u;
        __syncthreads();
        ps[t] += v;
        __syncthreads();
    }
    {
        unsigned S3 = (t < 255) ? ps[t + 1] : 0u;
        unsigned Sb = S3 + h3[t];
        if (Sb >= m2 && S3 < m2) { t3_sh = (unsigned)t; ca3_sh = S3; }
    }
    __syncthreads();
    unsigned tau = (b12 << 20) | (s2 << 8) | t3_sh;
    unsigned r = m2 - ca3_sh;                // exact-tie keepers
    int* ties = reinterpret_cast<int*>(sel_l);
    for (unsigned i = t; i < n2; i += 256) {
        uint2 c = cand2[i];
        if (((c.x >> 8) & 0xFFFu) != s2) continue;
        if (c.x > tau) {
            out[c.y] = __uint_as_float(c.x);
        } else if (c.x == tau) {
            unsigned q = atomicAdd(&tie_cnt, 1u);
            if (q < 2 * SELCAP) ties[q] = (int)c.y;
        }
    }
    __syncthreads();
    unsigned tc = tie_cnt; if (tc > 2 * SELCAP) tc = 2 * SELCAP;
    float tv = __uint_as_float(tau);
    for (unsigned e = t; e < tc; e += 256) {
        int my = ties[e];
        unsigned rank = 0u;
        for (unsigned j = 0; j < tc; ++j) rank += (ties[j] < my) ? 1u : 0u;
        if (rank < r) out[my] = tv;          // keep r lowest-index ties
    }
}

extern "C" void kernel_launch(void* const* d_in, const int* in_sizes, int n_in,
                              void* d_out, int out_size, void* d_ws, size_t ws_size,
                              hipStream_t stream) {
    const float4* x = (const float4*)d_in[0];
    const int* kptr = (const int*)d_in[1];
    float* out = (float*)d_out;
    unsigned* ws32 = (unsigned*)d_ws;
    uint2* sel   = (uint2*)(ws32 + SEL_OFF);
    uint2* cand2 = (uint2*)(ws32 + CAND2_OFF);
    uint2* cand  = (uint2*)(ws32 + CAND_OFF);

    unsigned cap = CAND_CAP;
    size_t hdr = (size_t)CAND_OFF * 4;
    if (ws_size < hdr + (size_t)CAND_CAP * 8) {
        cap = (ws_size > hdr) ? (unsigned)((ws_size - hdr) / 8) : 0u;
    }

    k_zero<<<64, 256, 0, stream>>>(ws32);
    k_sample<<<8, 256, 0, stream>>>(x, ws32);
    k_main<<<2048, 256, 0, stream>>>(x, (float4*)out, ws32, cand, cap, kptr);
    k_fb<<<2048, 256, 0, stream>>>(x, ws32, cand, cap, kptr);   // guarded no-op
    k_filter<<<256, 256, 0, stream>>>(ws32, cand, cand2, out, cap, kptr);
    k_sel_a<<<256, 256, 0, stream>>>(ws32, cand2, sel, out, kptr);
    k_sel_b<<<1, 256, 0, stream>>>(ws32, cand2, sel, out, kptr);
}